// Round 3
// baseline (223.865 us; speedup 1.0000x reference)
//
#include <hip/hip_runtime.h>
#include <math.h>

// MEASUREMENT ROUND: kernel body is byte-identical to R2. We launch it 4x
// (idempotent: each launch writes the identical output) to expose the true
// per-kernel duration T via dur_us = OH + 4*T, given R2's OH + T = 145.9 us.
// The harness poison fills (512 MB @ ~85 us + 134 MB @ ~21 us) dominate
// dur_us and hide our kernel (<80 us) from rocprof's top-5.
//
// GaussianRBF: y[b,s,o] = exp(-||(x[b,s]-mu[o])/sigma[o]||^2), normalized
// over o. 32768 points; O=1024; D=3. Output 134 MB f32 -> write-BW bound,
// floor = 134 MB / 6.25 TB/s (in-situ fill rate) = 21.5 us.

#define O_DIM 1024
#define NPOINTS (8 * 4096)
#define BLOCKS 2048            // 8192 waves -> exactly 4 points/wave

typedef float vf4 __attribute__((ext_vector_type(4)));

__global__ __launch_bounds__(256)
void GaussianRBF_83330955477629_kernel(const float* __restrict__ x,
                                       const float* __restrict__ mus,
                                       const float* __restrict__ log_sigmas,
                                       float* __restrict__ y) {
    const int lane = threadIdx.x & 63;
    const int wave = blockIdx.x * 4 + (threadIdx.x >> 6);
    const int nwav = BLOCKS * 4;

    // ---- per-lane constants for its 16 outputs (64 VGPRs) ----
    float mu0[16], mu1[16], mu2[16], w[16];   // w = 1/sigma^2 = exp(-2*ls)
#pragma unroll
    for (int j = 0; j < 4; ++j) {
        const int o = j * 256 + lane * 4;      // 4 consecutive outputs
        const vf4 m0 = *(const vf4*)(mus + 3 * o);
        const vf4 m1 = *(const vf4*)(mus + 3 * o + 4);
        const vf4 m2 = *(const vf4*)(mus + 3 * o + 8);
        mu0[j*4+0] = m0[0]; mu1[j*4+0] = m0[1]; mu2[j*4+0] = m0[2];
        mu0[j*4+1] = m0[3]; mu1[j*4+1] = m1[0]; mu2[j*4+1] = m1[1];
        mu0[j*4+2] = m1[2]; mu1[j*4+2] = m1[3]; mu2[j*4+2] = m2[0];
        mu0[j*4+3] = m2[1]; mu1[j*4+3] = m2[2]; mu2[j*4+3] = m2[3];
        const vf4 ls = *(const vf4*)(log_sigmas + o);
        w[j*4+0] = __expf(-2.0f * ls[0]);
        w[j*4+1] = __expf(-2.0f * ls[1]);
        w[j*4+2] = __expf(-2.0f * ls[2]);
        w[j*4+3] = __expf(-2.0f * ls[3]);
    }

    // ---- 4 points per wave, processed as 2 interleaved pairs ----
#pragma unroll
    for (int it = 0; it < 2; ++it) {
        const int p0 = wave + (2 * it + 0) * nwav;
        const int p1 = wave + (2 * it + 1) * nwav;

        const float a0 = x[p0 * 3 + 0], a1 = x[p0 * 3 + 1], a2 = x[p0 * 3 + 2];
        const float b0 = x[p1 * 3 + 0], b1 = x[p1 * 3 + 1], b2 = x[p1 * 3 + 2];

        float yv0[16], yv1[16];
        float s0 = 0.0f, s1 = 0.0f;
#pragma unroll
        for (int k = 0; k < 16; ++k) {
            const float d0 = a0 - mu0[k], d1 = a1 - mu1[k], d2 = a2 - mu2[k];
            const float e0 = b0 - mu0[k], e1 = b1 - mu1[k], e2 = b2 - mu2[k];
            const float q0 = d0 * d0 + d1 * d1 + d2 * d2;
            const float q1 = e0 * e0 + e1 * e1 + e2 * e2;
            const float v0 = __expf(-w[k] * q0);
            const float v1 = __expf(-w[k] * q1);
            yv0[k] = v0; s0 += v0;
            yv1[k] = v1; s1 += v1;
        }
        // two independent 64-lane butterflies, interleaved
#pragma unroll
        for (int off = 32; off; off >>= 1) {
            s0 += __shfl_xor(s0, off, 64);
            s1 += __shfl_xor(s1, off, 64);
        }
        const float r0 = __builtin_amdgcn_rcpf(s0);
        const float r1 = __builtin_amdgcn_rcpf(s1);

        float* yp0 = y + (size_t)p0 * O_DIM;
        float* yp1 = y + (size_t)p1 * O_DIM;
#pragma unroll
        for (int j = 0; j < 4; ++j) {
            vf4 o0, o1;
            o0[0] = yv0[j*4+0] * r0; o0[1] = yv0[j*4+1] * r0;
            o0[2] = yv0[j*4+2] * r0; o0[3] = yv0[j*4+3] * r0;
            o1[0] = yv1[j*4+0] * r1; o1[1] = yv1[j*4+1] * r1;
            o1[2] = yv1[j*4+2] * r1; o1[3] = yv1[j*4+3] * r1;
            __builtin_nontemporal_store(o0, (vf4*)(yp0 + j * 256 + lane * 4));
            __builtin_nontemporal_store(o1, (vf4*)(yp1 + j * 256 + lane * 4));
        }
    }
}

extern "C" void kernel_launch(void* const* d_in, const int* in_sizes, int n_in,
                              void* d_out, int out_size, void* d_ws, size_t ws_size,
                              hipStream_t stream) {
    const float* x  = (const float*)d_in[0];
    const float* mu = (const float*)d_in[1];
    const float* ls = (const float*)d_in[2];
    float* y = (float*)d_out;
    // 4x identical launches: measurement probe (dur_us = OH + 4*T).
    for (int i = 0; i < 4; ++i) {
        GaussianRBF_83330955477629_kernel<<<BLOCKS, 256, 0, stream>>>(x, mu, ls, y);
    }
}

// Round 4
// 215.214 us; speedup vs baseline: 1.0402x; 1.0402x over previous
//
#include <hip/hip_runtime.h>
#include <math.h>

// PROBE ROUND 2: body is byte-identical to the R1 kernel (plain float4
// stores, 1024 blocks, single-point loop, full-precision div), launched 4x.
// R3 probe established OH ~= 119.9 us, T(R2 body) ~= 26.0 us. Back-solved
// T(R1 body) ~= 21.4 us == write floor (134 MB / 6.3 TB/s). Hypothesis:
// R2's pair-interleave crossed the 128-VGPR occupancy cliff and/or nt
// stores defeat L2 write-combining. If right: dur_us ~= 206. If ~224:
// both bodies ~26 us and R1's reading was OH noise.

#define O_DIM 1024
#define NPOINTS (8 * 4096)
#define BLOCKS 1024   // 4096 waves total -> 8 points per wave

__global__ __launch_bounds__(256, 4)
void GaussianRBF_83330955477629_kernel(const float* __restrict__ x,
                                       const float* __restrict__ mus,
                                       const float* __restrict__ log_sigmas,
                                       float* __restrict__ y) {
    const int lane  = threadIdx.x & 63;
    const int wave  = blockIdx.x * (blockDim.x >> 6) + (threadIdx.x >> 6);
    const int nwav  = gridDim.x * (blockDim.x >> 6);

    // ---- per-lane constants for its 16 outputs ----
    float mu0[16], mu1[16], mu2[16], w[16];   // w = 1/sigma^2 = exp(-2*log_sigma)
#pragma unroll
    for (int j = 0; j < 4; ++j) {
        const int o = j * 256 + lane * 4;          // 4 consecutive outputs
        const float4 m0 = *(const float4*)(mus + 3 * o);
        const float4 m1 = *(const float4*)(mus + 3 * o + 4);
        const float4 m2 = *(const float4*)(mus + 3 * o + 8);
        mu0[j*4+0] = m0.x; mu1[j*4+0] = m0.y; mu2[j*4+0] = m0.z;
        mu0[j*4+1] = m0.w; mu1[j*4+1] = m1.x; mu2[j*4+1] = m1.y;
        mu0[j*4+2] = m1.z; mu1[j*4+2] = m1.w; mu2[j*4+2] = m2.x;
        mu0[j*4+3] = m2.y; mu1[j*4+3] = m2.z; mu2[j*4+3] = m2.w;
        const float4 ls = *(const float4*)(log_sigmas + o);
        w[j*4+0] = __expf(-2.0f * ls.x);
        w[j*4+1] = __expf(-2.0f * ls.y);
        w[j*4+2] = __expf(-2.0f * ls.z);
        w[j*4+3] = __expf(-2.0f * ls.w);
    }

    // ---- grid-stride over points; one wave handles a full point ----
    for (int p = wave; p < NPOINTS; p += nwav) {
        const float x0 = x[p * 3 + 0];
        const float x1 = x[p * 3 + 1];
        const float x2 = x[p * 3 + 2];

        float yv[16];
        float s = 0.0f;
#pragma unroll
        for (int k = 0; k < 16; ++k) {
            const float d0 = x0 - mu0[k];
            const float d1 = x1 - mu1[k];
            const float d2 = x2 - mu2[k];
            const float q  = d0 * d0 + d1 * d1 + d2 * d2;
            const float v  = __expf(-w[k] * q);
            yv[k] = v;
            s += v;
        }
        // wave-wide sum (64 lanes)
#pragma unroll
        for (int off = 32; off; off >>= 1) s += __shfl_xor(s, off, 64);
        const float r = 1.0f / s;

        float* yp = y + (size_t)p * O_DIM;
#pragma unroll
        for (int j = 0; j < 4; ++j) {
            float4 out;
            out.x = yv[j*4+0] * r;
            out.y = yv[j*4+1] * r;
            out.z = yv[j*4+2] * r;
            out.w = yv[j*4+3] * r;
            *(float4*)(yp + j * 256 + lane * 4) = out;  // coalesced 1 KB/wave
        }
    }
}

extern "C" void kernel_launch(void* const* d_in, const int* in_sizes, int n_in,
                              void* d_out, int out_size, void* d_ws, size_t ws_size,
                              hipStream_t stream) {
    const float* x  = (const float*)d_in[0];
    const float* mu = (const float*)d_in[1];
    const float* ls = (const float*)d_in[2];
    float* y = (float*)d_out;
    // 4x identical launches: measurement probe (dur_us = OH + 4*T).
    for (int i = 0; i < 4; ++i) {
        GaussianRBF_83330955477629_kernel<<<BLOCKS, 256, 0, stream>>>(x, mu, ls, y);
    }
}

// Round 5
// 140.494 us; speedup vs baseline: 1.5934x; 1.5318x over previous
//
#include <hip/hip_runtime.h>
#include <math.h>

// GaussianRBF: y[b,s,o] = exp(-||(x[b,s]-mu[o])/sigma[o]||^2), normalized
// over o. B*S=32768 points; O=1024; D=3. Output 134 MB f32.
//
// FINAL KERNEL (R1 body — best measured). Probe rounds R3/R4 (4x launches)
// established: T(this body) ~= 21.4-23.8 us vs the 21.3 us write floor
// (134 MB / 6.3 TB/s in-situ fill rate). Within-probe A/B: this body beats
// the pair-interleaved + nontemporal-store variant by 2.2 us/launch
// (nt stores / extra register pressure regressed). The remaining <=2.4 us
// gap is below the +-5 us harness-fill noise in dur_us -> at roofline.
//
// Structure: one wave per point; lane l owns outputs o = j*256 + l*4 + c
// -> every float4 store is a fully coalesced 1 KB wave-write. mu / 1/sigma^2
// register-resident (loaded once per wave, amortized over 8 points).
// Normalization sum via 6-step shfl_xor butterfly; VALU (~7 us) fully
// hidden under the write stream.

#define O_DIM 1024
#define NPOINTS (8 * 4096)
#define BLOCKS 1024   // 4096 waves total -> 8 points per wave; 4 blocks/CU

__global__ __launch_bounds__(256, 4)
void GaussianRBF_83330955477629_kernel(const float* __restrict__ x,
                                       const float* __restrict__ mus,
                                       const float* __restrict__ log_sigmas,
                                       float* __restrict__ y) {
    const int lane  = threadIdx.x & 63;
    const int wave  = blockIdx.x * (blockDim.x >> 6) + (threadIdx.x >> 6);
    const int nwav  = gridDim.x * (blockDim.x >> 6);

    // ---- per-lane constants for its 16 outputs ----
    float mu0[16], mu1[16], mu2[16], w[16];   // w = 1/sigma^2 = exp(-2*log_sigma)
#pragma unroll
    for (int j = 0; j < 4; ++j) {
        const int o = j * 256 + lane * 4;          // 4 consecutive outputs
        const float4 m0 = *(const float4*)(mus + 3 * o);
        const float4 m1 = *(const float4*)(mus + 3 * o + 4);
        const float4 m2 = *(const float4*)(mus + 3 * o + 8);
        mu0[j*4+0] = m0.x; mu1[j*4+0] = m0.y; mu2[j*4+0] = m0.z;
        mu0[j*4+1] = m0.w; mu1[j*4+1] = m1.x; mu2[j*4+1] = m1.y;
        mu0[j*4+2] = m1.z; mu1[j*4+2] = m1.w; mu2[j*4+2] = m2.x;
        mu0[j*4+3] = m2.y; mu1[j*4+3] = m2.z; mu2[j*4+3] = m2.w;
        const float4 ls = *(const float4*)(log_sigmas + o);
        w[j*4+0] = __expf(-2.0f * ls.x);
        w[j*4+1] = __expf(-2.0f * ls.y);
        w[j*4+2] = __expf(-2.0f * ls.z);
        w[j*4+3] = __expf(-2.0f * ls.w);
    }

    // ---- grid-stride over points; one wave handles a full point ----
    for (int p = wave; p < NPOINTS; p += nwav) {
        const float x0 = x[p * 3 + 0];
        const float x1 = x[p * 3 + 1];
        const float x2 = x[p * 3 + 2];

        float yv[16];
        float s = 0.0f;
#pragma unroll
        for (int k = 0; k < 16; ++k) {
            const float d0 = x0 - mu0[k];
            const float d1 = x1 - mu1[k];
            const float d2 = x2 - mu2[k];
            const float q  = d0 * d0 + d1 * d1 + d2 * d2;
            const float v  = __expf(-w[k] * q);
            yv[k] = v;
            s += v;
        }
        // wave-wide sum (64 lanes)
#pragma unroll
        for (int off = 32; off; off >>= 1) s += __shfl_xor(s, off, 64);
        const float r = 1.0f / s;

        float* yp = y + (size_t)p * O_DIM;
#pragma unroll
        for (int j = 0; j < 4; ++j) {
            float4 out;
            out.x = yv[j*4+0] * r;
            out.y = yv[j*4+1] * r;
            out.z = yv[j*4+2] * r;
            out.w = yv[j*4+3] * r;
            *(float4*)(yp + j * 256 + lane * 4) = out;  // coalesced 1 KB/wave
        }
    }
}

extern "C" void kernel_launch(void* const* d_in, const int* in_sizes, int n_in,
                              void* d_out, int out_size, void* d_ws, size_t ws_size,
                              hipStream_t stream) {
    const float* x  = (const float*)d_in[0];
    const float* mu = (const float*)d_in[1];
    const float* ls = (const float*)d_in[2];
    float* y = (float*)d_out;
    GaussianRBF_83330955477629_kernel<<<BLOCKS, 256, 0, stream>>>(x, mu, ls, y);
}